// Round 8
// baseline (489.348 us; speedup 1.0000x reference)
//
#include <hip/hip_runtime.h>

static constexpr int Bb = 32;
static constexpr int Tt = 4096;
static constexpr int Hh = 768;

// ---------------------------------------------------------------------------
// AUDITED BASELINE (held since r7; no successful bench yet — all infra).
// Structure: 2-pass chunked masked mean/std.
//
// Pass 1: per-(batch, t-chunk) partial sums / sums-of-squares over valid rows.
//
// Validity decided LOCALLY from the monotone mask (+1...+1,-1...-1):
//   valid t satisfies t < length, length = (first negative idx)+1, or T if
//   none. The first negative row IS included (reference: argmax+1).
// Chunk dead iff mask[t0-1] < 0 (uniform broadcast load, immediate return).
// Exactly one chunk per batch writes lengths[b]: the one containing the
// first negative, or the last chunk when the batch is full-length.
//
// 192 threads/block, each owns 4 consecutive h (float4 -> one contiguous
// 3072 B row per iteration, perfectly coalesced). t-loop unrolled x4 for 4
// independent 16 B loads in flight per lane.
// ---------------------------------------------------------------------------
__global__ __launch_bounds__(192) void partial_kernel(
        const float* __restrict__ x,
        const float* __restrict__ mask,
        int* __restrict__ lengths,
        float* __restrict__ sums,
        float* __restrict__ sqs,
        int nc, int tc) {
    const int b = blockIdx.x / nc;
    const int c = blockIdx.x % nc;
    const int t0 = c * tc;
    const float* mrow = mask + (size_t)b * Tt;

    if (t0 > 0 && mrow[t0 - 1] < 0.0f) return;   // fully past length

    // chunk-local first-negative index (relative), tc if none
    int jmin = tc;
    for (int j = threadIdx.x; j < tc; j += 192)
        if (mrow[t0 + j] < 0.0f) jmin = min(jmin, j);
    #pragma unroll
    for (int off = 32; off >= 1; off >>= 1)
        jmin = min(jmin, __shfl_down(jmin, off, 64));
    __shared__ int sj[3];
    if ((threadIdx.x & 63) == 0) sj[threadIdx.x >> 6] = jmin;
    __syncthreads();
    jmin = min(sj[0], min(sj[1], sj[2]));

    // unique per-batch length writer
    if (threadIdx.x == 0 && (jmin < tc || c == nc - 1))
        lengths[b] = (jmin < tc) ? (t0 + jmin + 1) : Tt;

    const int n = min(jmin + 1, tc);             // valid rows in this chunk

    const int h4 = threadIdx.x * 4;
    const float* p = x + ((size_t)b * Tt + t0) * Hh + h4;

    float s0 = 0.f, s1 = 0.f, s2 = 0.f, s3 = 0.f;
    float q0 = 0.f, q1 = 0.f, q2 = 0.f, q3 = 0.f;

    const int nfull = n & ~3;
    int t = 0;
    for (; t < nfull; t += 4) {
        const float4 v0 = *reinterpret_cast<const float4*>(p);
        const float4 v1 = *reinterpret_cast<const float4*>(p + Hh);
        const float4 v2 = *reinterpret_cast<const float4*>(p + 2 * Hh);
        const float4 v3 = *reinterpret_cast<const float4*>(p + 3 * Hh);
        p += 4 * Hh;
        s0 += v0.x + v1.x + v2.x + v3.x;
        s1 += v0.y + v1.y + v2.y + v3.y;
        s2 += v0.z + v1.z + v2.z + v3.z;
        s3 += v0.w + v1.w + v2.w + v3.w;
        q0 = fmaf(v0.x, v0.x, fmaf(v1.x, v1.x, fmaf(v2.x, v2.x, fmaf(v3.x, v3.x, q0))));
        q1 = fmaf(v0.y, v0.y, fmaf(v1.y, v1.y, fmaf(v2.y, v2.y, fmaf(v3.y, v3.y, q1))));
        q2 = fmaf(v0.z, v0.z, fmaf(v1.z, v1.z, fmaf(v2.z, v2.z, fmaf(v3.z, v3.z, q2))));
        q3 = fmaf(v0.w, v0.w, fmaf(v1.w, v1.w, fmaf(v2.w, v2.w, fmaf(v3.w, v3.w, q3))));
    }
    for (; t < n; ++t) {
        const float4 v = *reinterpret_cast<const float4*>(p);
        p += Hh;
        s0 += v.x; s1 += v.y; s2 += v.z; s3 += v.w;
        q0 = fmaf(v.x, v.x, q0);
        q1 = fmaf(v.y, v.y, q1);
        q2 = fmaf(v.z, v.z, q2);
        q3 = fmaf(v.w, v.w, q3);
    }

    const size_t o = ((size_t)(b * nc + c)) * Hh + h4;
    *reinterpret_cast<float4*>(sums + o) = make_float4(s0, s1, s2, s3);
    *reinterpret_cast<float4*>(sqs + o)  = make_float4(q0, q1, q2, q3);
}

// ---------------------------------------------------------------------------
// Pass 2: reduce valid chunks -> mean/std, write [B, 2H].
// Grid: B * (H/64) blocks, 256 threads = 64 h-columns x 4 chunk-slices,
// LDS reduce across slices. Deterministic summation order.
// ---------------------------------------------------------------------------
__global__ __launch_bounds__(256) void finalize_kernel(
        const float* __restrict__ sums,
        const float* __restrict__ sqs,
        const int* __restrict__ lengths,
        float* __restrict__ out,
        int nc, int tc) {
    const int nhb = Hh / 64;                  // 12
    const int b = blockIdx.x / nhb;
    const int hblk = blockIdx.x % nhb;
    const int hl = threadIdx.x & 63;
    const int cs = threadIdx.x >> 6;          // 0..3
    const int h = hblk * 64 + hl;

    const int length = lengths[b];
    const int ncv = (length + tc - 1) / tc;   // chunks pass 1 wrote

    float S = 0.f, Q = 0.f;
    for (int c = cs; c < ncv; c += 4) {
        const size_t o = ((size_t)(b * nc + c)) * Hh + h;
        S += sums[o];
        Q += sqs[o];
    }

    __shared__ float sS[4][64];
    __shared__ float sQ[4][64];
    sS[cs][hl] = S;
    sQ[cs][hl] = Q;
    __syncthreads();

    if (threadIdx.x < 64) {
        S = sS[0][hl] + sS[1][hl] + sS[2][hl] + sS[3][hl];
        Q = sQ[0][hl] + sQ[1][hl] + sQ[2][hl] + sQ[3][hl];
        const float cnt = (float)length;
        const float mean = S / cnt;
        const float var = (Q - S * S / cnt) / (cnt - 1.0f);
        out[(size_t)b * (2 * Hh) + h]      = mean;
        out[(size_t)b * (2 * Hh) + Hh + h] = sqrtf(fmaxf(var, 0.0f));
    }
}

// ---------------------------------------------------------------------------
// Fallback: one block per batch, no workspace partials needed (used only if
// ws_size is too small for even nc=1 chunking — eliminates any OOB path).
// ---------------------------------------------------------------------------
__global__ __launch_bounds__(192) void monolithic_kernel(
        const float* __restrict__ x,
        const float* __restrict__ mask,
        float* __restrict__ out) {
    const int b = blockIdx.x;
    const float* mrow = mask + (size_t)b * Tt;

    int jmin = Tt;
    for (int j = threadIdx.x; j < Tt; j += 192)
        if (mrow[j] < 0.0f) jmin = min(jmin, j);
    #pragma unroll
    for (int off = 32; off >= 1; off >>= 1)
        jmin = min(jmin, __shfl_down(jmin, off, 64));
    __shared__ int sj[3];
    if ((threadIdx.x & 63) == 0) sj[threadIdx.x >> 6] = jmin;
    __syncthreads();
    jmin = min(sj[0], min(sj[1], sj[2]));
    const int length = (jmin < Tt) ? jmin + 1 : Tt;

    const int h4 = threadIdx.x * 4;
    const float* p = x + (size_t)b * Tt * Hh + h4;
    float s0 = 0.f, s1 = 0.f, s2 = 0.f, s3 = 0.f;
    float q0 = 0.f, q1 = 0.f, q2 = 0.f, q3 = 0.f;
    for (int t = 0; t < length; ++t) {
        const float4 v = *reinterpret_cast<const float4*>(p);
        p += Hh;
        s0 += v.x; s1 += v.y; s2 += v.z; s3 += v.w;
        q0 = fmaf(v.x, v.x, q0);
        q1 = fmaf(v.y, v.y, q1);
        q2 = fmaf(v.z, v.z, q2);
        q3 = fmaf(v.w, v.w, q3);
    }
    const float cnt = (float)length;
    float* ob = out + (size_t)b * (2 * Hh);
    #pragma unroll
    for (int k = 0; k < 4; ++k) {
        const float S = (k == 0) ? s0 : (k == 1) ? s1 : (k == 2) ? s2 : s3;
        const float Q = (k == 0) ? q0 : (k == 1) ? q1 : (k == 2) ? q2 : q3;
        const float mean = S / cnt;
        const float var = (Q - S * S / cnt) / (cnt - 1.0f);
        ob[h4 + k]      = mean;
        ob[Hh + h4 + k] = sqrtf(fmaxf(var, 0.0f));
    }
}

// ---------------------------------------------------------------------------
extern "C" void kernel_launch(void* const* d_in, const int* in_sizes, int n_in,
                              void* d_out, int out_size, void* d_ws, size_t ws_size,
                              hipStream_t stream) {
    const float* feat = (const float*)d_in[0];   // [B, T, H] fp32
    const float* mask = (const float*)d_in[1];   // [B, T]    fp32
    float* out = (float*)d_out;                  // [B, 2H]   fp32

    // partials = B*nc*H*2 floats; shrink nc if workspace is tight
    int nc = 128;
    while (nc > 1 && (size_t)Bb * nc * Hh * 2 * sizeof(float) + 256 > ws_size) nc >>= 1;

    if ((size_t)Bb * nc * Hh * 2 * sizeof(float) + 256 > ws_size) {
        // workspace unusable -> safe monolithic path
        monolithic_kernel<<<Bb, 192, 0, stream>>>(feat, mask, out);
        return;
    }
    const int tc = Tt / nc;

    int*   lengths = (int*)d_ws;                       // 128 B
    float* sums    = (float*)((char*)d_ws + 256);      // [B][nc][H]
    float* sqs     = sums + (size_t)Bb * nc * Hh;      // [B][nc][H]

    partial_kernel<<<Bb * nc, 192, 0, stream>>>(feat, mask, lengths, sums, sqs, nc, tc);
    finalize_kernel<<<Bb * (Hh / 64), 256, 0, stream>>>(sums, sqs, lengths, out, nc, tc);
}

// Round 9
// 488.090 us; speedup vs baseline: 1.0026x; 1.0026x over previous
//
#include <hip/hip_runtime.h>

static constexpr int Bb = 32;
static constexpr int Tt = 4096;
static constexpr int Hh = 768;

// ---------------------------------------------------------------------------
// 2-pass chunked masked mean/std. r9: nc 128->64 (halve partial traffic).
//
// Pass 1: per-(batch, t-chunk) partial sums / sums-of-squares over valid rows.
// Validity decided LOCALLY from the monotone mask (+1...+1,-1...-1):
//   valid t satisfies t < length, length = (first negative idx)+1, or T if
//   none. The first negative row IS included (reference: argmax+1).
// Chunk dead iff mask[t0-1] < 0 (uniform broadcast load, immediate return).
// Exactly one chunk per batch writes lengths[b].
//
// 192 threads/block, each owns 4 consecutive h (float4 -> one contiguous
// 3072 B row per iteration, perfectly coalesced). t-loop unrolled x4 for 4
// independent 16 B loads in flight per lane.
// ---------------------------------------------------------------------------
__global__ __launch_bounds__(192) void partial_kernel(
        const float* __restrict__ x,
        const float* __restrict__ mask,
        int* __restrict__ lengths,
        float* __restrict__ sums,
        float* __restrict__ sqs,
        int nc, int tc) {
    const int b = blockIdx.x / nc;
    const int c = blockIdx.x % nc;
    const int t0 = c * tc;
    const float* mrow = mask + (size_t)b * Tt;

    if (t0 > 0 && mrow[t0 - 1] < 0.0f) return;   // fully past length

    // chunk-local first-negative index (relative), tc if none
    int jmin = tc;
    for (int j = threadIdx.x; j < tc; j += 192)
        if (mrow[t0 + j] < 0.0f) jmin = min(jmin, j);
    #pragma unroll
    for (int off = 32; off >= 1; off >>= 1)
        jmin = min(jmin, __shfl_down(jmin, off, 64));
    __shared__ int sj[3];
    if ((threadIdx.x & 63) == 0) sj[threadIdx.x >> 6] = jmin;
    __syncthreads();
    jmin = min(sj[0], min(sj[1], sj[2]));

    // unique per-batch length writer
    if (threadIdx.x == 0 && (jmin < tc || c == nc - 1))
        lengths[b] = (jmin < tc) ? (t0 + jmin + 1) : Tt;

    const int n = min(jmin + 1, tc);             // valid rows in this chunk

    const int h4 = threadIdx.x * 4;
    const float* p = x + ((size_t)b * Tt + t0) * Hh + h4;

    float s0 = 0.f, s1 = 0.f, s2 = 0.f, s3 = 0.f;
    float q0 = 0.f, q1 = 0.f, q2 = 0.f, q3 = 0.f;

    const int nfull = n & ~3;
    int t = 0;
    for (; t < nfull; t += 4) {
        const float4 v0 = *reinterpret_cast<const float4*>(p);
        const float4 v1 = *reinterpret_cast<const float4*>(p + Hh);
        const float4 v2 = *reinterpret_cast<const float4*>(p + 2 * Hh);
        const float4 v3 = *reinterpret_cast<const float4*>(p + 3 * Hh);
        p += 4 * Hh;
        s0 += v0.x + v1.x + v2.x + v3.x;
        s1 += v0.y + v1.y + v2.y + v3.y;
        s2 += v0.z + v1.z + v2.z + v3.z;
        s3 += v0.w + v1.w + v2.w + v3.w;
        q0 = fmaf(v0.x, v0.x, fmaf(v1.x, v1.x, fmaf(v2.x, v2.x, fmaf(v3.x, v3.x, q0))));
        q1 = fmaf(v0.y, v0.y, fmaf(v1.y, v1.y, fmaf(v2.y, v2.y, fmaf(v3.y, v3.y, q1))));
        q2 = fmaf(v0.z, v0.z, fmaf(v1.z, v1.z, fmaf(v2.z, v2.z, fmaf(v3.z, v3.z, q2))));
        q3 = fmaf(v0.w, v0.w, fmaf(v1.w, v1.w, fmaf(v2.w, v2.w, fmaf(v3.w, v3.w, q3))));
    }
    for (; t < n; ++t) {
        const float4 v = *reinterpret_cast<const float4*>(p);
        p += Hh;
        s0 += v.x; s1 += v.y; s2 += v.z; s3 += v.w;
        q0 = fmaf(v.x, v.x, q0);
        q1 = fmaf(v.y, v.y, q1);
        q2 = fmaf(v.z, v.z, q2);
        q3 = fmaf(v.w, v.w, q3);
    }

    const size_t o = ((size_t)(b * nc + c)) * Hh + h4;
    *reinterpret_cast<float4*>(sums + o) = make_float4(s0, s1, s2, s3);
    *reinterpret_cast<float4*>(sqs + o)  = make_float4(q0, q1, q2, q3);
}

// ---------------------------------------------------------------------------
// Pass 2: reduce valid chunks -> mean/std, write [B, 2H].
// Grid: B * (H/64) blocks, 256 threads = 64 h-columns x 4 chunk-slices,
// LDS reduce across slices. Deterministic summation order.
// ---------------------------------------------------------------------------
__global__ __launch_bounds__(256) void finalize_kernel(
        const float* __restrict__ sums,
        const float* __restrict__ sqs,
        const int* __restrict__ lengths,
        float* __restrict__ out,
        int nc, int tc) {
    const int nhb = Hh / 64;                  // 12
    const int b = blockIdx.x / nhb;
    const int hblk = blockIdx.x % nhb;
    const int hl = threadIdx.x & 63;
    const int cs = threadIdx.x >> 6;          // 0..3
    const int h = hblk * 64 + hl;

    const int length = lengths[b];
    const int ncv = (length + tc - 1) / tc;   // chunks pass 1 wrote

    float S = 0.f, Q = 0.f;
    for (int c = cs; c < ncv; c += 4) {
        const size_t o = ((size_t)(b * nc + c)) * Hh + h;
        S += sums[o];
        Q += sqs[o];
    }

    __shared__ float sS[4][64];
    __shared__ float sQ[4][64];
    sS[cs][hl] = S;
    sQ[cs][hl] = Q;
    __syncthreads();

    if (threadIdx.x < 64) {
        S = sS[0][hl] + sS[1][hl] + sS[2][hl] + sS[3][hl];
        Q = sQ[0][hl] + sQ[1][hl] + sQ[2][hl] + sQ[3][hl];
        const float cnt = (float)length;
        const float mean = S / cnt;
        const float var = (Q - S * S / cnt) / (cnt - 1.0f);
        out[(size_t)b * (2 * Hh) + h]      = mean;
        out[(size_t)b * (2 * Hh) + Hh + h] = sqrtf(fmaxf(var, 0.0f));
    }
}

// ---------------------------------------------------------------------------
// Fallback: one block per batch, no workspace partials needed (used only if
// ws_size is too small for even nc=1 chunking — eliminates any OOB path).
// ---------------------------------------------------------------------------
__global__ __launch_bounds__(192) void monolithic_kernel(
        const float* __restrict__ x,
        const float* __restrict__ mask,
        float* __restrict__ out) {
    const int b = blockIdx.x;
    const float* mrow = mask + (size_t)b * Tt;

    int jmin = Tt;
    for (int j = threadIdx.x; j < Tt; j += 192)
        if (mrow[j] < 0.0f) jmin = min(jmin, j);
    #pragma unroll
    for (int off = 32; off >= 1; off >>= 1)
        jmin = min(jmin, __shfl_down(jmin, off, 64));
    __shared__ int sj[3];
    if ((threadIdx.x & 63) == 0) sj[threadIdx.x >> 6] = jmin;
    __syncthreads();
    jmin = min(sj[0], min(sj[1], sj[2]));
    const int length = (jmin < Tt) ? jmin + 1 : Tt;

    const int h4 = threadIdx.x * 4;
    const float* p = x + (size_t)b * Tt * Hh + h4;
    float s0 = 0.f, s1 = 0.f, s2 = 0.f, s3 = 0.f;
    float q0 = 0.f, q1 = 0.f, q2 = 0.f, q3 = 0.f;
    for (int t = 0; t < length; ++t) {
        const float4 v = *reinterpret_cast<const float4*>(p);
        p += Hh;
        s0 += v.x; s1 += v.y; s2 += v.z; s3 += v.w;
        q0 = fmaf(v.x, v.x, q0);
        q1 = fmaf(v.y, v.y, q1);
        q2 = fmaf(v.z, v.z, q2);
        q3 = fmaf(v.w, v.w, q3);
    }
    const float cnt = (float)length;
    float* ob = out + (size_t)b * (2 * Hh);
    #pragma unroll
    for (int k = 0; k < 4; ++k) {
        const float S = (k == 0) ? s0 : (k == 1) ? s1 : (k == 2) ? s2 : s3;
        const float Q = (k == 0) ? q0 : (k == 1) ? q1 : (k == 2) ? q2 : q3;
        const float mean = S / cnt;
        const float var = (Q - S * S / cnt) / (cnt - 1.0f);
        ob[h4 + k]      = mean;
        ob[Hh + h4 + k] = sqrtf(fmaxf(var, 0.0f));
    }
}

// ---------------------------------------------------------------------------
extern "C" void kernel_launch(void* const* d_in, const int* in_sizes, int n_in,
                              void* d_out, int out_size, void* d_ws, size_t ws_size,
                              hipStream_t stream) {
    const float* feat = (const float*)d_in[0];   // [B, T, H] fp32
    const float* mask = (const float*)d_in[1];   // [B, T]    fp32
    float* out = (float*)d_out;                  // [B, 2H]   fp32

    // partials = B*nc*H*2 floats; shrink nc if workspace is tight
    int nc = 64;
    while (nc > 1 && (size_t)Bb * nc * Hh * 2 * sizeof(float) + 256 > ws_size) nc >>= 1;

    if ((size_t)Bb * nc * Hh * 2 * sizeof(float) + 256 > ws_size) {
        // workspace unusable -> safe monolithic path
        monolithic_kernel<<<Bb, 192, 0, stream>>>(feat, mask, out);
        return;
    }
    const int tc = Tt / nc;

    int*   lengths = (int*)d_ws;                       // 128 B
    float* sums    = (float*)((char*)d_ws + 256);      // [B][nc][H]
    float* sqs     = sums + (size_t)Bb * nc * Hh;      // [B][nc][H]

    partial_kernel<<<Bb * nc, 192, 0, stream>>>(feat, mask, lengths, sums, sqs, nc, tc);
    finalize_kernel<<<Bb * (Hh / 64), 256, 0, stream>>>(sums, sqs, lengths, out, nc, tc);
}